// Round 6
// baseline (196.540 us; speedup 1.0000x reference)
//
#include <hip/hip_runtime.h>

static constexpr int BB = 16;
static constexpr int NN = 256;
static constexpr int DD = 128;

// q = x@Wq^T + bq ; k = x@Wk^T ; v = x@Wv^T.  Outputs: eq=exp(-q), ek=exp(-k), v raw.
// grid = 3 m * 16 b * 32 row-tiles = 1536 blocks (6/CU), 256 threads.
__global__ __launch_bounds__(256) void qkv_kernel(
    const float* __restrict__ x,
    const float* __restrict__ Wq, const float* __restrict__ bq,
    const float* __restrict__ Wk, const float* __restrict__ Wv,
    float* __restrict__ eq, float* __restrict__ ek, float* __restrict__ vv)
{
    __shared__ float xs[8][DD];
    const int bid  = blockIdx.x;
    const int m    = bid % 3;
    const int tile = bid / 3;            // 0..511
    const int b    = tile >> 5;
    const int r0   = (tile & 31) << 3;   // 8-row tile
    const int t    = threadIdx.x;

    ((float4*)&xs[0][0])[t] = ((const float4*)(x + ((size_t)(b * NN + r0)) * DD))[t];
    __syncthreads();

    const int te = t & 31;               // e = te*4 + ee
    const int tr = t >> 5;               // one row per thread
    const float* W = (m == 0) ? Wq : (m == 1) ? Wk : Wv;
    float*      op = (m == 0) ? eq : (m == 1) ? ek : vv;

    float acc[4] = {0.f, 0.f, 0.f, 0.f};
    const float* xr = &xs[tr][0];
    #pragma unroll 4
    for (int d4 = 0; d4 < DD / 4; ++d4) {
        const float4 xv = *(const float4*)(xr + (d4 << 2));
        #pragma unroll
        for (int ee = 0; ee < 4; ++ee) {
            const float4 w = *(const float4*)(W + (size_t)(te * 4 + ee) * DD + (d4 << 2));
            acc[ee] = fmaf(xv.x, w.x, fmaf(xv.y, w.y, fmaf(xv.z, w.z, fmaf(xv.w, w.w, acc[ee]))));
        }
    }
    float4 o;
    if (m == 0) {
        const float4 b4 = ((const float4*)bq)[te];
        o.x = __expf(-(acc[0] + b4.x)); o.y = __expf(-(acc[1] + b4.y));
        o.z = __expf(-(acc[2] + b4.z)); o.w = __expf(-(acc[3] + b4.w));
    } else if (m == 1) {
        o.x = __expf(-acc[0]); o.y = __expf(-acc[1]);
        o.z = __expf(-acc[2]); o.w = __expf(-acc[3]);
    } else {
        o = make_float4(acc[0], acc[1], acc[2], acc[3]);
    }
    *(float4*)(op + ((size_t)(b * NN + r0 + tr)) * DD + (te << 2)) = o;
}

// grid = 16 b * 64 j-tiles = 1024 blocks, 512 threads, 4 j per block.
// LDS 40.5KB, VGPR capped for 8 waves/SIMD -> 4 blocks/CU (100% occupancy).
// Phase B: s[i][j] = edge ? sum_d We_d / (1 + ek[i,d]*eq[j,d]) : 0.5*sum(We)
// Phase C: softmax over i (waves 0-3) overlapped with v chunk-0 staging (waves 4-7).
// Phase D: v chunk in LDS, one b128 read feeds 4 j-accumulators (reg reuse).
__global__ __launch_bounds__(512, 8) void attn_kernel(
    const int* __restrict__ A, const float* __restrict__ We,
    const float* __restrict__ eq, const float* __restrict__ ek,
    const float* __restrict__ vv, float* __restrict__ out)
{
    __shared__ float vs[64][132];    // v chunk; reused as reduction buffer (33792 B)
    __shared__ float eqs[4][132];
    __shared__ float wes[DD];
    __shared__ float ssm[4][264];
    __shared__ float smC;

    // bijective XCD swizzle: 1024 wgs / 8 XCDs = 128 contiguous per XCD (2 batches each)
    const int bid = (int)((blockIdx.x & 7) * 128 + (blockIdx.x >> 3));
    const int b  = bid >> 6;
    const int j0 = (bid & 63) << 2;
    const int t  = threadIdx.x;

    // ---- Phase A: stage 4 q-rows + We; wave 7 computes C = 0.5*sum(We) ----
    if (t < 128) {
        const int row = t >> 5, col = (t & 31) << 2;
        *(float4*)&eqs[row][col] =
            *(const float4*)(eq + ((size_t)(b * NN + j0 + row)) * DD + col);
    } else if (t < 160) {
        const int l = t - 128;
        *(float4*)&wes[l << 2] = ((const float4*)We)[l];
    } else if (t >= 448) {
        const int lane = t - 448;
        float w = We[lane] + We[lane + 64];
        #pragma unroll
        for (int o = 32; o > 0; o >>= 1) w += __shfl_xor(w, o);
        if (lane == 0) smC = 0.5f * w;
    }
    __syncthreads();

    // ---- Phase B: all 256 i in one pass, 2 adjacent j per thread ----
    {
        const float C = smC;
        const int i  = t >> 1;
        const int jA = (t & 1) << 1;     // j = jA, jA+1
        const float4* ekr = (const float4*)(ek + ((size_t)(b * NN + i)) * DD);
        const int2 a2 = *(const int2*)(A + ((size_t)(b * NN + i)) * NN + j0 + jA);
        float acc0 = 0.f, acc1 = 0.f;
        #pragma unroll 4
        for (int d4 = 0; d4 < DD / 4; ++d4) {
            const float4 kv = ekr[d4];
            const float4 we = *(const float4*)&wes[d4 << 2];
            const float4 q0 = *(const float4*)&eqs[jA][d4 << 2];
            const float4 q1 = *(const float4*)&eqs[jA + 1][d4 << 2];
            acc0 += we.x * __builtin_amdgcn_rcpf(fmaf(kv.x, q0.x, 1.0f))
                  + we.y * __builtin_amdgcn_rcpf(fmaf(kv.y, q0.y, 1.0f))
                  + we.z * __builtin_amdgcn_rcpf(fmaf(kv.z, q0.z, 1.0f))
                  + we.w * __builtin_amdgcn_rcpf(fmaf(kv.w, q0.w, 1.0f));
            acc1 += we.x * __builtin_amdgcn_rcpf(fmaf(kv.x, q1.x, 1.0f))
                  + we.y * __builtin_amdgcn_rcpf(fmaf(kv.y, q1.y, 1.0f))
                  + we.z * __builtin_amdgcn_rcpf(fmaf(kv.z, q1.z, 1.0f))
                  + we.w * __builtin_amdgcn_rcpf(fmaf(kv.w, q1.w, 1.0f));
        }
        ssm[jA][i]     = (a2.x == 1) ? acc0 : C;
        ssm[jA + 1][i] = (a2.y == 1) ? acc1 : C;
    }
    __syncthreads();

    // ---- Phase C: softmax (waves 0-3) || stage v chunk 0 (waves 4-7) ----
    {
        const int wave = t >> 6;
        if (wave < 4) {
            const int c = t & 63;
            float vals[4];
            float mx = -1e30f;
            #pragma unroll
            for (int u = 0; u < 4; ++u) { vals[u] = ssm[wave][c + (u << 6)]; mx = fmaxf(mx, vals[u]); }
            #pragma unroll
            for (int o = 32; o > 0; o >>= 1) mx = fmaxf(mx, __shfl_xor(mx, o));
            float sum = 0.0f;
            #pragma unroll
            for (int u = 0; u < 4; ++u) { vals[u] = __expf(vals[u] - mx); sum += vals[u]; }
            #pragma unroll
            for (int o = 32; o > 0; o >>= 1) sum += __shfl_xor(sum, o);
            const float inv = __builtin_amdgcn_rcpf(sum);
            #pragma unroll
            for (int u = 0; u < 4; ++u) ssm[wave][c + (u << 6)] = vals[u] * inv;
        } else {
            const int t2 = t - 256;
            const float4* vg = (const float4*)(vv + (size_t)b * NN * DD);
            #pragma unroll
            for (int rep = 0; rep < 8; ++rep) {
                const int f = t2 + (rep << 8);          // 0..2047 over 8 reps
                *(float4*)&vs[f >> 5][(f & 31) << 2] = vg[f];
            }
        }
    }
    __syncthreads();

    // ---- Phase D: 4 chunks of 64 i; reg-reuse v4 across 4 j ----
    const int c4 = t & 31;       // d = c4*4 .. c4*4+3
    const int ig = t >> 5;       // 16 i-groups of 4
    float4 pa0 = {0,0,0,0}, pa1 = {0,0,0,0}, pa2 = {0,0,0,0}, pa3 = {0,0,0,0};
    for (int ch = 0; ch < 4; ++ch) {
        #pragma unroll
        for (int ii = 0; ii < 4; ++ii) {
            const int il = (ig << 2) + ii;
            const int i  = (ch << 6) + il;
            const float4 v4 = *(const float4*)&vs[il][c4 << 2];
            const float a0 = ssm[0][i], a1 = ssm[1][i], a2 = ssm[2][i], a3 = ssm[3][i];
            pa0.x = fmaf(a0, v4.x, pa0.x); pa0.y = fmaf(a0, v4.y, pa0.y);
            pa0.z = fmaf(a0, v4.z, pa0.z); pa0.w = fmaf(a0, v4.w, pa0.w);
            pa1.x = fmaf(a1, v4.x, pa1.x); pa1.y = fmaf(a1, v4.y, pa1.y);
            pa1.z = fmaf(a1, v4.z, pa1.z); pa1.w = fmaf(a1, v4.w, pa1.w);
            pa2.x = fmaf(a2, v4.x, pa2.x); pa2.y = fmaf(a2, v4.y, pa2.y);
            pa2.z = fmaf(a2, v4.z, pa2.z); pa2.w = fmaf(a2, v4.w, pa2.w);
            pa3.x = fmaf(a3, v4.x, pa3.x); pa3.y = fmaf(a3, v4.y, pa3.y);
            pa3.z = fmaf(a3, v4.z, pa3.z); pa3.w = fmaf(a3, v4.w, pa3.w);
        }
        if (ch < 3) {
            __syncthreads();
            const float4* vg = (const float4*)(vv + ((size_t)(b * NN) + ((ch + 1) << 6)) * DD);
            #pragma unroll
            for (int rep = 0; rep < 4; ++rep) {
                const int f = t + (rep << 9);           // 0..2047 over 4 reps
                *(float4*)&vs[f >> 5][(f & 31) << 2] = vg[f];
            }
            __syncthreads();
        }
    }
    __syncthreads();                                    // vs reads done -> reuse as red

    // ---- reduce 16 partials per (j,d), then store ----
    float* red = &vs[0][0];                             // [16][512] floats = 32KB
    *(float4*)&red[ig * 512 +   0 + (c4 << 2)] = pa0;
    *(float4*)&red[ig * 512 + 128 + (c4 << 2)] = pa1;
    *(float4*)&red[ig * 512 + 256 + (c4 << 2)] = pa2;
    *(float4*)&red[ig * 512 + 384 + (c4 << 2)] = pa3;
    __syncthreads();
    float s = 0.f;
    #pragma unroll
    for (int g = 0; g < 16; ++g) s += red[g * 512 + t];
    out[((size_t)(b * NN) + j0 + (t >> 7)) * DD + (t & 127)] = s;
}

extern "C" void kernel_launch(void* const* d_in, const int* in_sizes, int n_in,
                              void* d_out, int out_size, void* d_ws, size_t ws_size,
                              hipStream_t stream)
{
    const float* x  = (const float*)d_in[0];
    const int*   A  = (const int*)  d_in[1];
    const float* Wq = (const float*)d_in[2];
    const float* bq = (const float*)d_in[3];
    const float* Wk = (const float*)d_in[4];
    const float* Wv = (const float*)d_in[5];
    const float* We = (const float*)d_in[6];
    float* out = (float*)d_out;

    float* eq = (float*)d_ws;
    float* ek = eq + (size_t)BB * NN * DD;
    float* vv = ek + (size_t)BB * NN * DD;

    qkv_kernel<<<3 * BB * (NN / 8), 256, 0, stream>>>(x, Wq, bq, Wk, Wv, eq, ek, vv);
    attn_kernel<<<BB * (NN / 4), 512, 0, stream>>>(A, We, eq, ek, vv, out);
}

// Round 7
// 120.071 us; speedup vs baseline: 1.6369x; 1.6369x over previous
//
#include <hip/hip_runtime.h>

static constexpr int BB = 16;
static constexpr int NN = 256;
static constexpr int DD = 128;

// Tiled GEMM: out[b, r, e] = sum_d x[b,r,d] * W[e,d]  (+bias, then exp(-.) for q,k)
// grid = 3 m * 16 b * 4 row-tiles = 192 blocks, 512 threads, 1 block/CU (99KB LDS).
// W staged TRANSPOSED in LDS (wlds[d][e], XOR-swizzled: b128 e-reads conflict-free),
// x-tile staged padded. All global reads coalesced, read exactly once per block.
__global__ __launch_bounds__(512) void qkv_kernel(
    const float* __restrict__ x,
    const float* __restrict__ Wq, const float* __restrict__ bq,
    const float* __restrict__ Wk, const float* __restrict__ Wv,
    float* __restrict__ eq, float* __restrict__ ek, float* __restrict__ vv)
{
    __shared__ float wlds[DD * DD];     // [d][e] linear, XOR-swizzled (64KB)
    __shared__ float xlds[64][132];     // [row][d] padded (33.8KB)

    const int bid  = blockIdx.x;
    const int m    = bid % 3;                  // uniform per block
    const int tile = bid / 3;                  // 0..63
    const int b    = tile >> 2;
    const int r0   = (tile & 3) << 6;          // 64-row tile
    const int t    = threadIdx.x;

    const float* W = (m == 0) ? Wq : (m == 1) ? Wk : Wv;
    float*      op = (m == 0) ? eq : (m == 1) ? ek : vv;

    // ---- stage W transposed: wlds[d][e] = W[e][d] ----
    // idx -> e = idx>>5, dq = idx&31 (d = dq*4+c). Global read coalesced (row-major).
    // Write byte = (d*DD + e)*4 ^ ((dq&7)<<4)  -> read-side conflict-free; write 4-way.
    char* wb = (char*)wlds;
    #pragma unroll
    for (int rep = 0; rep < 8; ++rep) {
        const int idx = t + (rep << 9);        // 0..4095
        const int e   = idx >> 5;
        const int dq  = idx & 31;
        const float4 wv4 = ((const float4*)(W + (size_t)e * DD))[dq];
        const int swz = (dq & 7) << 4;
        const int base = (dq * 4 * DD + e) * 4;
        *(float*)(wb + ((base           ) ^ swz)) = wv4.x;
        *(float*)(wb + ((base + DD * 4  ) ^ swz)) = wv4.y;
        *(float*)(wb + ((base + DD * 8  ) ^ swz)) = wv4.z;
        *(float*)(wb + ((base + DD * 12 ) ^ swz)) = wv4.w;
    }
    // ---- stage x tile: 64 rows x 128 d ----
    {
        const float4* xg = (const float4*)(x + ((size_t)(b * NN + r0)) * DD);
        #pragma unroll
        for (int rep = 0; rep < 4; ++rep) {
            const int idx = t + (rep << 9);    // 0..2047
            *(float4*)&xlds[idx >> 5][(idx & 31) << 2] = xg[idx];
        }
    }
    __syncthreads();

    // ---- compute: thread = 4 rows (rg*4+rr) x 4 e (er*4..) ----
    const int er = t & 31;                     // e0 = er*4
    const int rg = t >> 5;                     // rows rg*4 .. rg*4+3
    float4 acc[4] = {{0,0,0,0},{0,0,0,0},{0,0,0,0},{0,0,0,0}};

    #pragma unroll 4
    for (int d4 = 0; d4 < DD / 4; ++d4) {
        const int swz = (d4 & 7) << 4;
        float4 w4[4];
        #pragma unroll
        for (int c = 0; c < 4; ++c)
            w4[c] = *(const float4*)(wb + ((((d4 * 4 + c) * DD + er * 4) * 4) ^ swz));
        #pragma unroll
        for (int rr = 0; rr < 4; ++rr) {
            const float4 xv = *(const float4*)&xlds[rg * 4 + rr][d4 << 2];  // broadcast
            acc[rr].x = fmaf(xv.x, w4[0].x, fmaf(xv.y, w4[1].x, fmaf(xv.z, w4[2].x, fmaf(xv.w, w4[3].x, acc[rr].x))));
            acc[rr].y = fmaf(xv.x, w4[0].y, fmaf(xv.y, w4[1].y, fmaf(xv.z, w4[2].y, fmaf(xv.w, w4[3].y, acc[rr].y))));
            acc[rr].z = fmaf(xv.x, w4[0].z, fmaf(xv.y, w4[1].z, fmaf(xv.z, w4[2].z, fmaf(xv.w, w4[3].z, acc[rr].z))));
            acc[rr].w = fmaf(xv.x, w4[0].w, fmaf(xv.y, w4[1].w, fmaf(xv.z, w4[2].w, fmaf(xv.w, w4[3].w, acc[rr].w))));
        }
    }

    // ---- epilogue: bias + exp(-.) for q,k; raw for v. Coalesced stores. ----
    float4 b4 = make_float4(0.f, 0.f, 0.f, 0.f);
    if (m == 0) b4 = ((const float4*)bq)[er];
    #pragma unroll
    for (int rr = 0; rr < 4; ++rr) {
        float4 o = acc[rr];
        if (m == 0) {
            o.x = __expf(-(o.x + b4.x)); o.y = __expf(-(o.y + b4.y));
            o.z = __expf(-(o.z + b4.z)); o.w = __expf(-(o.w + b4.w));
        } else if (m == 1) {
            o.x = __expf(-o.x); o.y = __expf(-o.y);
            o.z = __expf(-o.z); o.w = __expf(-o.w);
        }
        *(float4*)(op + ((size_t)(b * NN + r0 + rg * 4 + rr)) * DD + (er << 2)) = o;
    }
}

// grid = 16 b * 64 j-tiles = 1024 blocks, 512 threads, 4 j per block.
// LDS 40.5KB, VGPR capped for 8 waves/SIMD -> 4 blocks/CU (100% occupancy).
// Phase B: s[i][j] = edge ? sum_d We_d / (1 + ek[i,d]*eq[j,d]) : 0.5*sum(We)
// Phase C: softmax over i (waves 0-3) overlapped with v chunk-0 staging (waves 4-7).
// Phase D: v chunk in LDS, one b128 read feeds 4 j-accumulators (reg reuse).
__global__ __launch_bounds__(512, 8) void attn_kernel(
    const int* __restrict__ A, const float* __restrict__ We,
    const float* __restrict__ eq, const float* __restrict__ ek,
    const float* __restrict__ vv, float* __restrict__ out)
{
    __shared__ float vs[64][132];    // v chunk; reused as reduction buffer (33792 B)
    __shared__ float eqs[4][132];
    __shared__ float wes[DD];
    __shared__ float ssm[4][264];
    __shared__ float smC;

    // bijective XCD swizzle: 1024 wgs / 8 XCDs = 128 contiguous per XCD (2 batches each)
    const int bid = (int)((blockIdx.x & 7) * 128 + (blockIdx.x >> 3));
    const int b  = bid >> 6;
    const int j0 = (bid & 63) << 2;
    const int t  = threadIdx.x;

    // ---- Phase A: stage 4 q-rows + We; wave 7 computes C = 0.5*sum(We) ----
    if (t < 128) {
        const int row = t >> 5, col = (t & 31) << 2;
        *(float4*)&eqs[row][col] =
            *(const float4*)(eq + ((size_t)(b * NN + j0 + row)) * DD + col);
    } else if (t < 160) {
        const int l = t - 128;
        *(float4*)&wes[l << 2] = ((const float4*)We)[l];
    } else if (t >= 448) {
        const int lane = t - 448;
        float w = We[lane] + We[lane + 64];
        #pragma unroll
        for (int o = 32; o > 0; o >>= 1) w += __shfl_xor(w, o);
        if (lane == 0) smC = 0.5f * w;
    }
    __syncthreads();

    // ---- Phase B: all 256 i in one pass, 2 adjacent j per thread ----
    {
        const float C = smC;
        const int i  = t >> 1;
        const int jA = (t & 1) << 1;     // j = jA, jA+1
        const float4* ekr = (const float4*)(ek + ((size_t)(b * NN + i)) * DD);
        const int2 a2 = *(const int2*)(A + ((size_t)(b * NN + i)) * NN + j0 + jA);
        float acc0 = 0.f, acc1 = 0.f;
        #pragma unroll 4
        for (int d4 = 0; d4 < DD / 4; ++d4) {
            const float4 kv = ekr[d4];
            const float4 we = *(const float4*)&wes[d4 << 2];
            const float4 q0 = *(const float4*)&eqs[jA][d4 << 2];
            const float4 q1 = *(const float4*)&eqs[jA + 1][d4 << 2];
            acc0 += we.x * __builtin_amdgcn_rcpf(fmaf(kv.x, q0.x, 1.0f))
                  + we.y * __builtin_amdgcn_rcpf(fmaf(kv.y, q0.y, 1.0f))
                  + we.z * __builtin_amdgcn_rcpf(fmaf(kv.z, q0.z, 1.0f))
                  + we.w * __builtin_amdgcn_rcpf(fmaf(kv.w, q0.w, 1.0f));
            acc1 += we.x * __builtin_amdgcn_rcpf(fmaf(kv.x, q1.x, 1.0f))
                  + we.y * __builtin_amdgcn_rcpf(fmaf(kv.y, q1.y, 1.0f))
                  + we.z * __builtin_amdgcn_rcpf(fmaf(kv.z, q1.z, 1.0f))
                  + we.w * __builtin_amdgcn_rcpf(fmaf(kv.w, q1.w, 1.0f));
        }
        ssm[jA][i]     = (a2.x == 1) ? acc0 : C;
        ssm[jA + 1][i] = (a2.y == 1) ? acc1 : C;
    }
    __syncthreads();

    // ---- Phase C: softmax (waves 0-3) || stage v chunk 0 (waves 4-7) ----
    {
        const int wave = t >> 6;
        if (wave < 4) {
            const int c = t & 63;
            float vals[4];
            float mx = -1e30f;
            #pragma unroll
            for (int u = 0; u < 4; ++u) { vals[u] = ssm[wave][c + (u << 6)]; mx = fmaxf(mx, vals[u]); }
            #pragma unroll
            for (int o = 32; o > 0; o >>= 1) mx = fmaxf(mx, __shfl_xor(mx, o));
            float sum = 0.0f;
            #pragma unroll
            for (int u = 0; u < 4; ++u) { vals[u] = __expf(vals[u] - mx); sum += vals[u]; }
            #pragma unroll
            for (int o = 32; o > 0; o >>= 1) sum += __shfl_xor(sum, o);
            const float inv = __builtin_amdgcn_rcpf(sum);
            #pragma unroll
            for (int u = 0; u < 4; ++u) ssm[wave][c + (u << 6)] = vals[u] * inv;
        } else {
            const int t2 = t - 256;
            const float4* vg = (const float4*)(vv + (size_t)b * NN * DD);
            #pragma unroll
            for (int rep = 0; rep < 8; ++rep) {
                const int f = t2 + (rep << 8);          // 0..2047 over 8 reps
                *(float4*)&vs[f >> 5][(f & 31) << 2] = vg[f];
            }
        }
    }
    __syncthreads();

    // ---- Phase D: 4 chunks of 64 i; reg-reuse v4 across 4 j ----
    const int c4 = t & 31;       // d = c4*4 .. c4*4+3
    const int ig = t >> 5;       // 16 i-groups of 4
    float4 pa0 = {0,0,0,0}, pa1 = {0,0,0,0}, pa2 = {0,0,0,0}, pa3 = {0,0,0,0};
    for (int ch = 0; ch < 4; ++ch) {
        #pragma unroll
        for (int ii = 0; ii < 4; ++ii) {
            const int il = (ig << 2) + ii;
            const int i  = (ch << 6) + il;
            const float4 v4 = *(const float4*)&vs[il][c4 << 2];
            const float a0 = ssm[0][i], a1 = ssm[1][i], a2 = ssm[2][i], a3 = ssm[3][i];
            pa0.x = fmaf(a0, v4.x, pa0.x); pa0.y = fmaf(a0, v4.y, pa0.y);
            pa0.z = fmaf(a0, v4.z, pa0.z); pa0.w = fmaf(a0, v4.w, pa0.w);
            pa1.x = fmaf(a1, v4.x, pa1.x); pa1.y = fmaf(a1, v4.y, pa1.y);
            pa1.z = fmaf(a1, v4.z, pa1.z); pa1.w = fmaf(a1, v4.w, pa1.w);
            pa2.x = fmaf(a2, v4.x, pa2.x); pa2.y = fmaf(a2, v4.y, pa2.y);
            pa2.z = fmaf(a2, v4.z, pa2.z); pa2.w = fmaf(a2, v4.w, pa2.w);
            pa3.x = fmaf(a3, v4.x, pa3.x); pa3.y = fmaf(a3, v4.y, pa3.y);
            pa3.z = fmaf(a3, v4.z, pa3.z); pa3.w = fmaf(a3, v4.w, pa3.w);
        }
        if (ch < 3) {
            __syncthreads();
            const float4* vg = (const float4*)(vv + ((size_t)(b * NN) + ((ch + 1) << 6)) * DD);
            #pragma unroll
            for (int rep = 0; rep < 4; ++rep) {
                const int f = t + (rep << 9);           // 0..2047 over 4 reps
                *(float4*)&vs[f >> 5][(f & 31) << 2] = vg[f];
            }
            __syncthreads();
        }
    }
    __syncthreads();                                    // vs reads done -> reuse as red

    // ---- reduce 16 partials per (j,d), then store ----
    float* red = &vs[0][0];                             // [16][512] floats = 32KB
    *(float4*)&red[ig * 512 +   0 + (c4 << 2)] = pa0;
    *(float4*)&red[ig * 512 + 128 + (c4 << 2)] = pa1;
    *(float4*)&red[ig * 512 + 256 + (c4 << 2)] = pa2;
    *(float4*)&red[ig * 512 + 384 + (c4 << 2)] = pa3;
    __syncthreads();
    float s = 0.f;
    #pragma unroll
    for (int g = 0; g < 16; ++g) s += red[g * 512 + t];
    out[((size_t)(b * NN) + j0 + (t >> 7)) * DD + (t & 127)] = s;
}

extern "C" void kernel_launch(void* const* d_in, const int* in_sizes, int n_in,
                              void* d_out, int out_size, void* d_ws, size_t ws_size,
                              hipStream_t stream)
{
    const float* x  = (const float*)d_in[0];
    const int*   A  = (const int*)  d_in[1];
    const float* Wq = (const float*)d_in[2];
    const float* bq = (const float*)d_in[3];
    const float* Wk = (const float*)d_in[4];
    const float* Wv = (const float*)d_in[5];
    const float* We = (const float*)d_in[6];
    float* out = (float*)d_out;

    float* eq = (float*)d_ws;
    float* ek = eq + (size_t)BB * NN * DD;
    float* vv = ek + (size_t)BB * NN * DD;

    qkv_kernel<<<3 * BB * (NN / 64), 512, 0, stream>>>(x, Wq, bq, Wk, Wv, eq, ek, vv);
    attn_kernel<<<BB * (NN / 4), 512, 0, stream>>>(A, We, eq, ek, vv, out);
}

// Round 8
// 106.248 us; speedup vs baseline: 1.8498x; 1.1301x over previous
//
#include <hip/hip_runtime.h>

static constexpr int BB = 16;
static constexpr int NN = 256;
static constexpr int DD = 128;

// Tiled GEMM: out[b, r, e] = sum_d x[b,r,d] * W[e,d]  (+bias, then exp(-.) for q,k)
// grid = 3 m * 16 b * 4 row-tiles = 192 blocks, 512 threads, 1 block/CU (99KB LDS).
// W staged TRANSPOSED in LDS (wlds[d][e], XOR-swizzled: b128 e-reads conflict-free),
// x-tile staged padded. All global reads coalesced, read exactly once per block.
__global__ __launch_bounds__(512) void qkv_kernel(
    const float* __restrict__ x,
    const float* __restrict__ Wq, const float* __restrict__ bq,
    const float* __restrict__ Wk, const float* __restrict__ Wv,
    float* __restrict__ eq, float* __restrict__ ek, float* __restrict__ vv)
{
    __shared__ float wlds[DD * DD];     // [d][e] linear, XOR-swizzled (64KB)
    __shared__ float xlds[64][132];     // [row][d] padded (33.8KB)

    const int bid  = blockIdx.x;
    const int m    = bid % 3;                  // uniform per block
    const int tile = bid / 3;                  // 0..63
    const int b    = tile >> 2;
    const int r0   = (tile & 3) << 6;          // 64-row tile
    const int t    = threadIdx.x;

    const float* W = (m == 0) ? Wq : (m == 1) ? Wk : Wv;
    float*      op = (m == 0) ? eq : (m == 1) ? ek : vv;

    // ---- stage W transposed: wlds[d][e] = W[e][d] ----
    char* wb = (char*)wlds;
    #pragma unroll
    for (int rep = 0; rep < 8; ++rep) {
        const int idx = t + (rep << 9);        // 0..4095
        const int e   = idx >> 5;
        const int dq  = idx & 31;
        const float4 wv4 = ((const float4*)(W + (size_t)e * DD))[dq];
        const int swz = (dq & 7) << 4;
        const int base = (dq * 4 * DD + e) * 4;
        *(float*)(wb + ((base           ) ^ swz)) = wv4.x;
        *(float*)(wb + ((base + DD * 4  ) ^ swz)) = wv4.y;
        *(float*)(wb + ((base + DD * 8  ) ^ swz)) = wv4.z;
        *(float*)(wb + ((base + DD * 12 ) ^ swz)) = wv4.w;
    }
    // ---- stage x tile: 64 rows x 128 d ----
    {
        const float4* xg = (const float4*)(x + ((size_t)(b * NN + r0)) * DD);
        #pragma unroll
        for (int rep = 0; rep < 4; ++rep) {
            const int idx = t + (rep << 9);    // 0..2047
            *(float4*)&xlds[idx >> 5][(idx & 31) << 2] = xg[idx];
        }
    }
    __syncthreads();

    // ---- compute: thread = 4 rows (rg*4+rr) x 4 e (er*4..) ----
    const int er = t & 31;                     // e0 = er*4
    const int rg = t >> 5;                     // rows rg*4 .. rg*4+3
    float4 acc[4] = {{0,0,0,0},{0,0,0,0},{0,0,0,0},{0,0,0,0}};

    #pragma unroll 4
    for (int d4 = 0; d4 < DD / 4; ++d4) {
        const int swz = (d4 & 7) << 4;
        float4 w4[4];
        #pragma unroll
        for (int c = 0; c < 4; ++c)
            w4[c] = *(const float4*)(wb + ((((d4 * 4 + c) * DD + er * 4) * 4) ^ swz));
        #pragma unroll
        for (int rr = 0; rr < 4; ++rr) {
            const float4 xv = *(const float4*)&xlds[rg * 4 + rr][d4 << 2];  // broadcast
            acc[rr].x = fmaf(xv.x, w4[0].x, fmaf(xv.y, w4[1].x, fmaf(xv.z, w4[2].x, fmaf(xv.w, w4[3].x, acc[rr].x))));
            acc[rr].y = fmaf(xv.x, w4[0].y, fmaf(xv.y, w4[1].y, fmaf(xv.z, w4[2].y, fmaf(xv.w, w4[3].y, acc[rr].y))));
            acc[rr].z = fmaf(xv.x, w4[0].z, fmaf(xv.y, w4[1].z, fmaf(xv.z, w4[2].z, fmaf(xv.w, w4[3].z, acc[rr].z))));
            acc[rr].w = fmaf(xv.x, w4[0].w, fmaf(xv.y, w4[1].w, fmaf(xv.z, w4[2].w, fmaf(xv.w, w4[3].w, acc[rr].w))));
        }
    }

    // ---- epilogue: bias + exp(-.) for q,k; raw for v. Coalesced stores. ----
    float4 b4 = make_float4(0.f, 0.f, 0.f, 0.f);
    if (m == 0) b4 = ((const float4*)bq)[er];
    #pragma unroll
    for (int rr = 0; rr < 4; ++rr) {
        float4 o = acc[rr];
        if (m == 0) {
            o.x = __expf(-(o.x + b4.x)); o.y = __expf(-(o.y + b4.y));
            o.z = __expf(-(o.z + b4.z)); o.w = __expf(-(o.w + b4.w));
        } else if (m == 1) {
            o.x = __expf(-o.x); o.y = __expf(-o.y);
            o.z = __expf(-o.z); o.w = __expf(-o.w);
        }
        *(float4*)(op + ((size_t)(b * NN + r0 + rg * 4 + rr)) * DD + (er << 2)) = o;
    }
}

// grid = 16 b * 64 j-tiles = 1024 blocks, 512 threads, 4 j per block.
// __launch_bounds__(512, 4): 128 VGPR/thread — NO SPILLS (R7: the ",8" variant
// pinned VGPR=32 and spilled 64MB/dispatch to scratch). 2 blocks/CU.
// Phase B: s[i][j] = edge ? sum_d We_d / (1 + ek[i,d]*eq[j,d]) : 0.5*sum(We)
// Phase C: softmax over i (waves 0-3) overlapped with v chunk-0 staging (waves 4-7).
// Phase D: v chunk in LDS, one b128 read feeds 4 j-accumulators (reg reuse).
__global__ __launch_bounds__(512, 4) void attn_kernel(
    const int* __restrict__ A, const float* __restrict__ We,
    const float* __restrict__ eq, const float* __restrict__ ek,
    const float* __restrict__ vv, float* __restrict__ out)
{
    __shared__ float vs[64][132];    // v chunk; reused as reduction buffer (33792 B)
    __shared__ float eqs[4][132];
    __shared__ float wes[DD];
    __shared__ float ssm[4][264];
    __shared__ float smC;

    // bijective XCD swizzle: 1024 wgs / 8 XCDs = 128 contiguous per XCD (2 batches each)
    const int bid = (int)((blockIdx.x & 7) * 128 + (blockIdx.x >> 3));
    const int b  = bid >> 6;
    const int j0 = (bid & 63) << 2;
    const int t  = threadIdx.x;

    // ---- Phase A: stage 4 q-rows + We; wave 7 computes C = 0.5*sum(We) ----
    if (t < 128) {
        const int row = t >> 5, col = (t & 31) << 2;
        *(float4*)&eqs[row][col] =
            *(const float4*)(eq + ((size_t)(b * NN + j0 + row)) * DD + col);
    } else if (t < 160) {
        const int l = t - 128;
        *(float4*)&wes[l << 2] = ((const float4*)We)[l];
    } else if (t >= 448) {
        const int lane = t - 448;
        float w = We[lane] + We[lane + 64];
        #pragma unroll
        for (int o = 32; o > 0; o >>= 1) w += __shfl_xor(w, o);
        if (lane == 0) smC = 0.5f * w;
    }
    __syncthreads();

    // ---- Phase B: all 256 i in one pass, 2 adjacent j per thread ----
    {
        const float C = smC;
        const int i  = t >> 1;
        const int jA = (t & 1) << 1;     // j = jA, jA+1
        const float4* ekr = (const float4*)(ek + ((size_t)(b * NN + i)) * DD);
        const int2 a2 = *(const int2*)(A + ((size_t)(b * NN + i)) * NN + j0 + jA);
        float acc0 = 0.f, acc1 = 0.f;
        #pragma unroll 4
        for (int d4 = 0; d4 < DD / 4; ++d4) {
            const float4 kv = ekr[d4];
            const float4 we = *(const float4*)&wes[d4 << 2];
            const float4 q0 = *(const float4*)&eqs[jA][d4 << 2];
            const float4 q1 = *(const float4*)&eqs[jA + 1][d4 << 2];
            acc0 += we.x * __builtin_amdgcn_rcpf(fmaf(kv.x, q0.x, 1.0f))
                  + we.y * __builtin_amdgcn_rcpf(fmaf(kv.y, q0.y, 1.0f))
                  + we.z * __builtin_amdgcn_rcpf(fmaf(kv.z, q0.z, 1.0f))
                  + we.w * __builtin_amdgcn_rcpf(fmaf(kv.w, q0.w, 1.0f));
            acc1 += we.x * __builtin_amdgcn_rcpf(fmaf(kv.x, q1.x, 1.0f))
                  + we.y * __builtin_amdgcn_rcpf(fmaf(kv.y, q1.y, 1.0f))
                  + we.z * __builtin_amdgcn_rcpf(fmaf(kv.z, q1.z, 1.0f))
                  + we.w * __builtin_amdgcn_rcpf(fmaf(kv.w, q1.w, 1.0f));
        }
        ssm[jA][i]     = (a2.x == 1) ? acc0 : C;
        ssm[jA + 1][i] = (a2.y == 1) ? acc1 : C;
    }
    __syncthreads();

    // ---- Phase C: softmax (waves 0-3) || stage v chunk 0 (waves 4-7) ----
    {
        const int wave = t >> 6;
        if (wave < 4) {
            const int c = t & 63;
            float vals[4];
            float mx = -1e30f;
            #pragma unroll
            for (int u = 0; u < 4; ++u) { vals[u] = ssm[wave][c + (u << 6)]; mx = fmaxf(mx, vals[u]); }
            #pragma unroll
            for (int o = 32; o > 0; o >>= 1) mx = fmaxf(mx, __shfl_xor(mx, o));
            float sum = 0.0f;
            #pragma unroll
            for (int u = 0; u < 4; ++u) { vals[u] = __expf(vals[u] - mx); sum += vals[u]; }
            #pragma unroll
            for (int o = 32; o > 0; o >>= 1) sum += __shfl_xor(sum, o);
            const float inv = __builtin_amdgcn_rcpf(sum);
            #pragma unroll
            for (int u = 0; u < 4; ++u) ssm[wave][c + (u << 6)] = vals[u] * inv;
        } else {
            const int t2 = t - 256;
            const float4* vg = (const float4*)(vv + (size_t)b * NN * DD);
            #pragma unroll
            for (int rep = 0; rep < 8; ++rep) {
                const int f = t2 + (rep << 8);          // 0..2047 over 8 reps
                *(float4*)&vs[f >> 5][(f & 31) << 2] = vg[f];
            }
        }
    }
    __syncthreads();

    // ---- Phase D: 4 chunks of 64 i; reg-reuse v4 across 4 j ----
    const int c4 = t & 31;       // d = c4*4 .. c4*4+3
    const int ig = t >> 5;       // 16 i-groups of 4
    float4 pa0 = {0,0,0,0}, pa1 = {0,0,0,0}, pa2 = {0,0,0,0}, pa3 = {0,0,0,0};
    for (int ch = 0; ch < 4; ++ch) {
        #pragma unroll
        for (int ii = 0; ii < 4; ++ii) {
            const int il = (ig << 2) + ii;
            const int i  = (ch << 6) + il;
            const float4 v4 = *(const float4*)&vs[il][c4 << 2];
            const float a0 = ssm[0][i], a1 = ssm[1][i], a2 = ssm[2][i], a3 = ssm[3][i];
            pa0.x = fmaf(a0, v4.x, pa0.x); pa0.y = fmaf(a0, v4.y, pa0.y);
            pa0.z = fmaf(a0, v4.z, pa0.z); pa0.w = fmaf(a0, v4.w, pa0.w);
            pa1.x = fmaf(a1, v4.x, pa1.x); pa1.y = fmaf(a1, v4.y, pa1.y);
            pa1.z = fmaf(a1, v4.z, pa1.z); pa1.w = fmaf(a1, v4.w, pa1.w);
            pa2.x = fmaf(a2, v4.x, pa2.x); pa2.y = fmaf(a2, v4.y, pa2.y);
            pa2.z = fmaf(a2, v4.z, pa2.z); pa2.w = fmaf(a2, v4.w, pa2.w);
            pa3.x = fmaf(a3, v4.x, pa3.x); pa3.y = fmaf(a3, v4.y, pa3.y);
            pa3.z = fmaf(a3, v4.z, pa3.z); pa3.w = fmaf(a3, v4.w, pa3.w);
        }
        if (ch < 3) {
            __syncthreads();
            const float4* vg = (const float4*)(vv + ((size_t)(b * NN) + ((ch + 1) << 6)) * DD);
            #pragma unroll
            for (int rep = 0; rep < 4; ++rep) {
                const int f = t + (rep << 9);           // 0..2047 over 4 reps
                *(float4*)&vs[f >> 5][(f & 31) << 2] = vg[f];
            }
            __syncthreads();
        }
    }
    __syncthreads();                                    // vs reads done -> reuse as red

    // ---- reduce 16 partials per (j,d), then store ----
    float* red = &vs[0][0];                             // [16][512] floats = 32KB
    *(float4*)&red[ig * 512 +   0 + (c4 << 2)] = pa0;
    *(float4*)&red[ig * 512 + 128 + (c4 << 2)] = pa1;
    *(float4*)&red[ig * 512 + 256 + (c4 << 2)] = pa2;
    *(float4*)&red[ig * 512 + 384 + (c4 << 2)] = pa3;
    __syncthreads();
    float s = 0.f;
    #pragma unroll
    for (int g = 0; g < 16; ++g) s += red[g * 512 + t];
    out[((size_t)(b * NN) + j0 + (t >> 7)) * DD + (t & 127)] = s;
}

extern "C" void kernel_launch(void* const* d_in, const int* in_sizes, int n_in,
                              void* d_out, int out_size, void* d_ws, size_t ws_size,
                              hipStream_t stream)
{
    const float* x  = (const float*)d_in[0];
    const int*   A  = (const int*)  d_in[1];
    const float* Wq = (const float*)d_in[2];
    const float* bq = (const float*)d_in[3];
    const float* Wk = (const float*)d_in[4];
    const float* Wv = (const float*)d_in[5];
    const float* We = (const float*)d_in[6];
    float* out = (float*)d_out;

    float* eq = (float*)d_ws;
    float* ek = eq + (size_t)BB * NN * DD;
    float* vv = ek + (size_t)BB * NN * DD;

    qkv_kernel<<<3 * BB * (NN / 64), 512, 0, stream>>>(x, Wq, bq, Wk, Wv, eq, ek, vv);
    attn_kernel<<<BB * (NN / 4), 512, 0, stream>>>(A, We, eq, ek, vv, out);
}